// Round 1
// baseline (367.209 us; speedup 1.0000x reference)
//
#include <hip/hip_runtime.h>
#include <float.h>
#include <math.h>

#define LL 32
#define BB 128
#define FF 4096
#define EE 512
#define HH 512
#define NLAYER 2
#define KK 20

// ---------------- K1: q[b][e] = mean_l enc_emb[tok[l][b]][e] ----------------
__global__ __launch_bounds__(256) void q_kernel(const int* __restrict__ tok,
                                                const float* __restrict__ emb,
                                                float* __restrict__ q) {
    int b = blockIdx.x;
    __shared__ int t_s[LL];
    if (threadIdx.x < LL) t_s[threadIdx.x] = tok[threadIdx.x * BB + b];
    __syncthreads();
    for (int e = threadIdx.x; e < EE; e += 256) {
        float acc = 0.f;
        #pragma unroll
        for (int l = 0; l < LL; ++l) acc += emb[(long)t_s[l] * EE + e];
        q[b * EE + e] = acc * (1.0f / LL);
    }
}

// ---------------- K2: scores[b][f] = dot(q[b], fact[b][f]) ----------------
// wave-per-row: each of 4 waves handles 8 consecutive f rows; lane holds 8
// floats of q (two float4 in the lane*4 / 256+lane*4 mapping).
__global__ __launch_bounds__(256) void scores_kernel(const float* __restrict__ q,
                                                     const float* __restrict__ fact,
                                                     float* __restrict__ scores) {
    int b = blockIdx.y;
    int wave = threadIdx.x >> 6;
    int lane = threadIdx.x & 63;
    const float4* qv = (const float4*)(q + b * EE);
    float4 qa = qv[lane];
    float4 qb = qv[64 + lane];
    int f0 = (blockIdx.x * 4 + wave) * 8;
    #pragma unroll
    for (int i = 0; i < 8; ++i) {
        int f = f0 + i;
        const float4* fv = (const float4*)(fact + ((long)b * FF + f) * EE);
        float4 fa = fv[lane];
        float4 fb = fv[64 + lane];
        float d = qa.x * fa.x + qa.y * fa.y + qa.z * fa.z + qa.w * fa.w
                + qb.x * fb.x + qb.y * fb.y + qb.z * fb.z + qb.w * fb.w;
        #pragma unroll
        for (int off = 32; off > 0; off >>= 1) d += __shfl_xor(d, off, 64);
        if (lane == 0) scores[b * FF + f] = d;
    }
}

// ---------------- K3: per-b top-20 (descending, ties -> lower idx) + gather ----------------
__global__ __launch_bounds__(256) void topk_kernel(const float* __restrict__ scores,
                                                   const float* __restrict__ fact,
                                                   float* __restrict__ topf) {
    int b = blockIdx.x;
    __shared__ float vals[FF];
    __shared__ float rv[256];
    __shared__ int ri[256];
    __shared__ int sel[KK];
    int t = threadIdx.x;
    for (int i = t; i < FF; i += 256) vals[i] = scores[b * FF + i];
    __syncthreads();
    for (int it = 0; it < KK; ++it) {
        float bv = -FLT_MAX;
        int bi = FF;
        for (int j = t; j < FF; j += 256) {
            float v = vals[j];
            if (v > bv) { bv = v; bi = j; }   // strict > => lower idx wins within thread
        }
        rv[t] = bv; ri[t] = bi;
        __syncthreads();
        for (int s = 128; s > 0; s >>= 1) {
            if (t < s) {
                float ov = rv[t + s]; int oi = ri[t + s];
                if (ov > rv[t] || (ov == rv[t] && oi < ri[t])) { rv[t] = ov; ri[t] = oi; }
            }
            __syncthreads();
        }
        if (t == 0) {
            int w = ri[0];
            sel[it] = w;
            vals[w] = -FLT_MAX;
        }
        __syncthreads();
    }
    // gather top-k fact rows into ws (coalesced float4 copies)
    for (int k = 0; k < KK; ++k) {
        int src = sel[k];
        const float4* s4 = (const float4*)(fact + ((long)b * FF + src) * EE);
        float4* d4 = (float4*)(topf + ((long)b * KK + k) * EE);
        for (int e = t; e < EE / 4; e += 256) d4[e] = s4[e];
    }
}

// ---------------- K4: update(h), update(c) fused ----------------
// 4 waves per block: wave w handles (u = h if w<2 else c, layer = w&1) for b.
__global__ __launch_bounds__(256) void update_kernel(const float* __restrict__ topf,
                                                     const float* __restrict__ hin,
                                                     const float* __restrict__ cin,
                                                     float* __restrict__ out) {
    int b = blockIdx.x;
    __shared__ float tf[KK][EE];   // 40 KiB
    for (int i = threadIdx.x; i < KK * EE; i += 256)
        tf[i >> 9][i & 511] = topf[(long)b * KK * EE + i];
    __syncthreads();
    int w = threadIdx.x >> 6, lane = threadIdx.x & 63;
    const float* u = (w < 2 ? hin : cin) + ((size_t)(w & 1) * BB + b) * EE;
    const float4* uv = (const float4*)u;
    float4 ua = uv[lane], ub = uv[64 + lane];
    float sk[KK];
    #pragma unroll
    for (int k = 0; k < KK; ++k) {
        const float4* tv = (const float4*)&tf[k][0];
        float4 ta = tv[lane], tb = tv[64 + lane];
        float d = ua.x * ta.x + ua.y * ta.y + ua.z * ta.z + ua.w * ta.w
                + ub.x * tb.x + ub.y * tb.y + ub.z * tb.z + ub.w * tb.w;
        #pragma unroll
        for (int off = 32; off > 0; off >>= 1) d += __shfl_xor(d, off, 64);
        sk[k] = d;   // butterfly => broadcast to all lanes
    }
    float m = sk[0];
    #pragma unroll
    for (int k = 1; k < KK; ++k) m = fmaxf(m, sk[k]);
    float sum = 0.f;
    #pragma unroll
    for (int k = 0; k < KK; ++k) { sk[k] = __expf(sk[k] - m); sum += sk[k]; }
    float inv = 1.f / sum;
    float4 oa = {0, 0, 0, 0}, ob = {0, 0, 0, 0};
    #pragma unroll
    for (int k = 0; k < KK; ++k) {
        float p = sk[k] * inv;
        const float4* tv = (const float4*)&tf[k][0];
        float4 ta = tv[lane], tb = tv[64 + lane];
        oa.x += p * ta.x; oa.y += p * ta.y; oa.z += p * ta.z; oa.w += p * ta.w;
        ob.x += p * tb.x; ob.y += p * tb.y; ob.z += p * tb.z; ob.w += p * tb.w;
    }
    oa.x += ua.x; oa.y += ua.y; oa.z += ua.z; oa.w += ua.w;
    ob.x += ub.x; ob.y += ub.y; ob.z += ub.z; ob.w += ub.w;
    float* obase = out + (size_t)(w < 2 ? 0 : NLAYER * BB * HH)
                       + ((size_t)(w & 1) * BB + b) * HH;
    float4* ov = (float4*)obase;
    ov[lane] = oa;
    ov[64 + lane] = ob;
}

// ---------------- K5: fact_M / fact_C ----------------
// grid (B, 2): block computes [20k x 512h] for one b, one matrix.
// thread t owns h in {t, t+256}, all 20 k; topf in LDS (broadcast reads),
// W rows streamed from global (L1-amortized).
__global__ __launch_bounds__(256) void factmc_kernel(const float* __restrict__ topf,
                                                     const float* __restrict__ Aw,
                                                     const float* __restrict__ Ab,
                                                     const float* __restrict__ Cw,
                                                     const float* __restrict__ Cb,
                                                     float* __restrict__ out) {
    int b = blockIdx.x;
    int mat = blockIdx.y;
    const float* W = mat ? Cw : Aw;
    const float* bias = mat ? Cb : Ab;
    float* O = out + (size_t)2 * NLAYER * BB * HH
                   + (size_t)mat * BB * KK * HH + (size_t)b * KK * HH;
    __shared__ float tf[KK][EE];   // 40 KiB
    for (int i = threadIdx.x; i < KK * EE; i += 256)
        tf[i >> 9][i & 511] = topf[(long)b * KK * EE + i];
    __syncthreads();
    int t = threadIdx.x;
    float acc0[KK], acc1[KK];
    #pragma unroll
    for (int k = 0; k < KK; ++k) { acc0[k] = 0.f; acc1[k] = 0.f; }
    const float4* w0 = (const float4*)(W + (size_t)t * EE);
    const float4* w1 = (const float4*)(W + (size_t)(t + 256) * EE);
    for (int e4 = 0; e4 < EE / 4; ++e4) {
        float4 a0 = w0[e4];
        float4 a1 = w1[e4];
        #pragma unroll
        for (int k = 0; k < KK; ++k) {
            float4 tv = *(const float4*)&tf[k][e4 * 4];
            acc0[k] += a0.x * tv.x + a0.y * tv.y + a0.z * tv.z + a0.w * tv.w;
            acc1[k] += a1.x * tv.x + a1.y * tv.y + a1.z * tv.z + a1.w * tv.w;
        }
    }
    float b0 = bias[t], b1 = bias[t + 256];
    #pragma unroll
    for (int k = 0; k < KK; ++k) {
        O[(size_t)k * HH + t] = acc0[k] + b0;
        O[(size_t)k * HH + t + 256] = acc1[k] + b1;
    }
}

extern "C" void kernel_launch(void* const* d_in, const int* in_sizes, int n_in,
                              void* d_out, int out_size, void* d_ws, size_t ws_size,
                              hipStream_t stream) {
    const int* tok = (const int*)d_in[0];
    const float* fact = (const float*)d_in[1];
    const float* hin = (const float*)d_in[2];
    const float* cin = (const float*)d_in[3];
    const float* emb = (const float*)d_in[4];
    const float* Aw = (const float*)d_in[5];
    const float* Ab = (const float*)d_in[6];
    const float* Cw = (const float*)d_in[7];
    const float* Cb = (const float*)d_in[8];
    float* out = (float*)d_out;

    float* ws = (float*)d_ws;
    float* q = ws;                               // 128*512          = 65536
    float* scores = ws + 65536;                  // 128*4096         = 524288
    float* topf = ws + 65536 + 524288;           // 128*20*512       = 1310720

    q_kernel<<<BB, 256, 0, stream>>>(tok, emb, q);
    scores_kernel<<<dim3(FF / 32, BB), 256, 0, stream>>>(q, fact, scores);
    topk_kernel<<<BB, 256, 0, stream>>>(scores, fact, topf);
    update_kernel<<<BB, 256, 0, stream>>>(topf, hin, cin, out);
    factmc_kernel<<<dim3(BB, 2), 256, 0, stream>>>(topf, Aw, Ab, Cw, Cb, out);
}

// Round 2
// 267.100 us; speedup vs baseline: 1.3748x; 1.3748x over previous
//
#include <hip/hip_runtime.h>
#include <float.h>
#include <math.h>

#define LL 32
#define BB 128
#define FF 4096
#define EE 512
#define HH 512
#define NLAYER 2
#define KK 20

typedef float f4 __attribute__((ext_vector_type(4)));

// ---------------- K1: q[b][e] = mean_l enc_emb[tok[l][b]][e] ----------------
// grid (BB, 2): block handles one 256-wide e-half of one b.
__global__ __launch_bounds__(256) void q_kernel(const int* __restrict__ tok,
                                                const float* __restrict__ emb,
                                                float* __restrict__ q) {
    int b = blockIdx.x, eh = blockIdx.y;
    __shared__ int ts[LL];
    if (threadIdx.x < LL) ts[threadIdx.x] = tok[threadIdx.x * BB + b];
    __syncthreads();
    int e = eh * 256 + threadIdx.x;
    float acc = 0.f;
    #pragma unroll
    for (int l = 0; l < LL; ++l) acc += emb[(long)ts[l] * EE + e];
    q[b * EE + e] = acc * (1.0f / LL);
}

// ---------------- K2: scores[b][f] = dot(q[b], fact[b][f]) ----------------
// wave-per-row, 8 rows per wave; fact streamed with non-temporal loads.
__global__ __launch_bounds__(256) void scores_kernel(const float* __restrict__ q,
                                                     const float* __restrict__ fact,
                                                     float* __restrict__ scores) {
    int b = blockIdx.y;
    int wave = threadIdx.x >> 6;
    int lane = threadIdx.x & 63;
    const f4* qv = (const f4*)(q + b * EE);
    f4 qa = qv[lane];
    f4 qb = qv[64 + lane];
    int f0 = (blockIdx.x * 4 + wave) * 8;
    #pragma unroll
    for (int i = 0; i < 8; ++i) {
        int f = f0 + i;
        const f4* fv = (const f4*)(fact + ((long)b * FF + f) * EE);
        f4 fa = __builtin_nontemporal_load(fv + lane);
        f4 fb = __builtin_nontemporal_load(fv + 64 + lane);
        f4 p = qa * fa + qb * fb;
        float d = p.x + p.y + p.z + p.w;
        #pragma unroll
        for (int off = 32; off > 0; off >>= 1) d += __shfl_xor(d, off, 64);
        if (lane == 0) scores[b * FF + f] = d;
    }
}

// ---------------- K3: top-20 + gather + update(h,c)  (fused, one block per b) ----------------
__global__ __launch_bounds__(256) void topk_update_kernel(const float* __restrict__ scores,
                                                          const float* __restrict__ fact,
                                                          const float* __restrict__ hin,
                                                          const float* __restrict__ cin,
                                                          float* __restrict__ topf,
                                                          float* __restrict__ out) {
    int b = blockIdx.x;
    __shared__ float vals[FF];                 // 16 KiB
    __shared__ float tf[KK][EE];               // 40 KiB
    __shared__ unsigned long long wbest[4];
    __shared__ int sel[KK];
    int t = threadIdx.x;
    int wave = t >> 6, lane = t & 63;

    // stage scores
    const float4* sv = (const float4*)(scores + b * FF);
    float4* vv = (float4*)vals;
    for (int i = t; i < FF / 4; i += 256) vv[i] = sv[i];
    __syncthreads();

    // 20 x argmax with packed (sortable-value | (FF-1-idx)) keys; ties -> lower idx
    for (int it = 0; it < KK; ++it) {
        unsigned long long best = 0;
        #pragma unroll
        for (int s = 0; s < FF / 256; ++s) {
            int j = t + s * 256;
            unsigned u = __float_as_uint(vals[j]);
            u ^= ((int)u >> 31) | 0x80000000u;
            unsigned long long key = ((unsigned long long)u << 32) | (unsigned)(FF - 1 - j);
            if (key > best) best = key;
        }
        #pragma unroll
        for (int off = 32; off > 0; off >>= 1) {
            unsigned hi = (unsigned)(best >> 32), lo = (unsigned)best;
            unsigned ohi = __shfl_xor(hi, off, 64);
            unsigned olo = __shfl_xor(lo, off, 64);
            unsigned long long o = ((unsigned long long)ohi << 32) | olo;
            if (o > best) best = o;
        }
        if (lane == 0) wbest[wave] = best;
        __syncthreads();
        if (t == 0) {
            unsigned long long bb = wbest[0];
            if (wbest[1] > bb) bb = wbest[1];
            if (wbest[2] > bb) bb = wbest[2];
            if (wbest[3] > bb) bb = wbest[3];
            int idx = FF - 1 - (int)(bb & 0xFFFFFFFFu);
            sel[it] = idx;
            vals[idx] = -FLT_MAX;
        }
        __syncthreads();
    }

    // gather 20 rows -> tf (LDS) and topf (global), 2 rows per pass
    for (int kk = 0; kk < KK; kk += 2) {
        int k = kk + (t >> 7);
        int e = t & 127;
        int src = sel[k];
        float4 v = *(const float4*)(fact + (((long)b * FF + src) * EE) + e * 4);
        *(float4*)&tf[k][e * 4] = v;
        *(float4*)(topf + (((long)b * KK + k) * EE) + e * 4) = v;
    }
    __syncthreads();

    // update: wave w -> (u = h if w<2 else c, layer = w&1)
    const float* u = (wave < 2 ? hin : cin) + ((size_t)(wave & 1) * BB + b) * EE;
    const float4* uv = (const float4*)u;
    float4 ua = uv[lane], ub = uv[64 + lane];
    float sk[KK];
    #pragma unroll
    for (int k = 0; k < KK; ++k) {
        const float4* tv = (const float4*)&tf[k][0];
        float4 ta = tv[lane], tb = tv[64 + lane];
        float d = ua.x * ta.x + ua.y * ta.y + ua.z * ta.z + ua.w * ta.w
                + ub.x * tb.x + ub.y * tb.y + ub.z * tb.z + ub.w * tb.w;
        #pragma unroll
        for (int off = 32; off > 0; off >>= 1) d += __shfl_xor(d, off, 64);
        sk[k] = d;
    }
    float m = sk[0];
    #pragma unroll
    for (int k = 1; k < KK; ++k) m = fmaxf(m, sk[k]);
    float sum = 0.f;
    #pragma unroll
    for (int k = 0; k < KK; ++k) { sk[k] = __expf(sk[k] - m); sum += sk[k]; }
    float inv = 1.f / sum;
    float4 oa = {0, 0, 0, 0}, ob = {0, 0, 0, 0};
    #pragma unroll
    for (int k = 0; k < KK; ++k) {
        float p = sk[k] * inv;
        const float4* tv = (const float4*)&tf[k][0];
        float4 ta = tv[lane], tb = tv[64 + lane];
        oa.x += p * ta.x; oa.y += p * ta.y; oa.z += p * ta.z; oa.w += p * ta.w;
        ob.x += p * tb.x; ob.y += p * tb.y; ob.z += p * tb.z; ob.w += p * tb.w;
    }
    oa.x += ua.x; oa.y += ua.y; oa.z += ua.z; oa.w += ua.w;
    ob.x += ub.x; ob.y += ub.y; ob.z += ub.z; ob.w += ub.w;
    float* obase = out + (size_t)(wave < 2 ? 0 : NLAYER * BB * HH)
                       + ((size_t)(wave & 1) * BB + b) * HH;
    float4* ov = (float4*)obase;
    ov[lane] = oa;
    ov[64 + lane] = ob;
}

// ---------------- K4: fact_M / fact_C ----------------
// grid (B, 2): block = one b, one matrix; 512 threads, thread t owns h=t.
__global__ __launch_bounds__(512) void factmc_kernel(const float* __restrict__ topf,
                                                     const float* __restrict__ Aw,
                                                     const float* __restrict__ Ab,
                                                     const float* __restrict__ Cw,
                                                     const float* __restrict__ Cb,
                                                     float* __restrict__ out) {
    int b = blockIdx.x;
    int mat = blockIdx.y;
    const float* W = mat ? Cw : Aw;
    const float* bias = mat ? Cb : Ab;
    float* O = out + (size_t)2 * NLAYER * BB * HH
                   + (size_t)mat * BB * KK * HH + (size_t)b * KK * HH;
    __shared__ float tf[KK][EE];   // 40 KiB
    for (int i = threadIdx.x; i < KK * EE; i += 512)
        tf[i >> 9][i & 511] = topf[(long)b * KK * EE + i];
    __syncthreads();
    int t = threadIdx.x;
    float acc[KK];
    #pragma unroll
    for (int k = 0; k < KK; ++k) acc[k] = 0.f;
    const float4* wr = (const float4*)(W + (size_t)t * EE);
    for (int e4 = 0; e4 < EE / 4; ++e4) {
        float4 a = wr[e4];
        #pragma unroll
        for (int k = 0; k < KK; ++k) {
            float4 tv = *(const float4*)&tf[k][e4 * 4];
            acc[k] += a.x * tv.x + a.y * tv.y + a.z * tv.z + a.w * tv.w;
        }
    }
    float bb = bias[t];
    #pragma unroll
    for (int k = 0; k < KK; ++k) O[(size_t)k * HH + t] = acc[k] + bb;
}

extern "C" void kernel_launch(void* const* d_in, const int* in_sizes, int n_in,
                              void* d_out, int out_size, void* d_ws, size_t ws_size,
                              hipStream_t stream) {
    const int* tok = (const int*)d_in[0];
    const float* fact = (const float*)d_in[1];
    const float* hin = (const float*)d_in[2];
    const float* cin = (const float*)d_in[3];
    const float* emb = (const float*)d_in[4];
    const float* Aw = (const float*)d_in[5];
    const float* Ab = (const float*)d_in[6];
    const float* Cw = (const float*)d_in[7];
    const float* Cb = (const float*)d_in[8];
    float* out = (float*)d_out;

    float* ws = (float*)d_ws;
    float* q = ws;                               // 128*512          = 65536
    float* scores = ws + 65536;                  // 128*4096         = 524288
    float* topf = ws + 65536 + 524288;           // 128*20*512       = 1310720

    q_kernel<<<dim3(BB, 2), 256, 0, stream>>>(tok, emb, q);
    scores_kernel<<<dim3(FF / 32, BB), 256, 0, stream>>>(q, fact, scores);
    topk_update_kernel<<<BB, 256, 0, stream>>>(scores, fact, hin, cin, topf, out);
    factmc_kernel<<<dim3(BB, 2), 512, 0, stream>>>(topf, Aw, Ab, Cw, Cb, out);
}

// Round 3
// 222.602 us; speedup vs baseline: 1.6496x; 1.1999x over previous
//
#include <hip/hip_runtime.h>
#include <float.h>
#include <math.h>

#define LL 32
#define BB 128
#define FF 4096
#define EE 512
#define HH 512
#define NLAYER 2
#define KK 20

typedef float f4 __attribute__((ext_vector_type(4)));
typedef short bf16x8 __attribute__((ext_vector_type(8)));
typedef float f32x4 __attribute__((ext_vector_type(4)));

__device__ inline unsigned short bf16rne(float x) {
    unsigned u = __float_as_uint(x);
    u += 0x7fff + ((u >> 16) & 1);
    return (unsigned short)(u >> 16);
}

// ---------------- K1: q[b][e] = mean_l enc_emb[tok[l][b]][e] ----------------
__global__ __launch_bounds__(256) void q_kernel(const int* __restrict__ tok,
                                                const float* __restrict__ emb,
                                                float* __restrict__ q) {
    int b = blockIdx.x, eh = blockIdx.y;
    __shared__ int ts[LL];
    if (threadIdx.x < LL) ts[threadIdx.x] = tok[threadIdx.x * BB + b];
    __syncthreads();
    int e = eh * 256 + threadIdx.x;
    float acc = 0.f;
    #pragma unroll
    for (int l = 0; l < LL; ++l) acc += emb[(long)ts[l] * EE + e];
    q[b * EE + e] = acc * (1.0f / LL);
}

// ---------------- K1b: convert Aw, Cw -> bf16 (runs every call; ~1 MB each) ----------------
__global__ __launch_bounds__(256) void convw_kernel(const float* __restrict__ Aw,
                                                    const float* __restrict__ Cw,
                                                    unsigned short* __restrict__ Wbf) {
    const float* W = blockIdx.y ? Cw : Aw;
    unsigned short* dst = Wbf + (size_t)blockIdx.y * HH * EE;
    int i = (blockIdx.x * 256 + threadIdx.x) * 4;
    float4 v = *(const float4*)(W + i);
    ushort4 o;
    o.x = bf16rne(v.x); o.y = bf16rne(v.y); o.z = bf16rne(v.z); o.w = bf16rne(v.w);
    *(ushort4*)(dst + i) = o;
}

// ---------------- K2: scores[b][f] = dot(q[b], fact[b][f]) ----------------
__global__ __launch_bounds__(256) void scores_kernel(const float* __restrict__ q,
                                                     const float* __restrict__ fact,
                                                     float* __restrict__ scores) {
    int b = blockIdx.y;
    int wave = threadIdx.x >> 6;
    int lane = threadIdx.x & 63;
    const f4* qv = (const f4*)(q + b * EE);
    f4 qa = qv[lane];
    f4 qb = qv[64 + lane];
    int f0 = (blockIdx.x * 4 + wave) * 8;
    #pragma unroll
    for (int i = 0; i < 8; ++i) {
        int f = f0 + i;
        const f4* fv = (const f4*)(fact + ((long)b * FF + f) * EE);
        f4 fa = __builtin_nontemporal_load(fv + lane);
        f4 fb = __builtin_nontemporal_load(fv + 64 + lane);
        f4 p = qa * fa + qb * fb;
        float d = p.x + p.y + p.z + p.w;
        #pragma unroll
        for (int off = 32; off > 0; off >>= 1) d += __shfl_xor(d, off, 64);
        if (lane == 0) scores[b * FF + f] = d;
    }
}

// ---------------- K3: top-20 + gather(->bf16) + update(h,c) fused ----------------
__global__ __launch_bounds__(256) void topk_update_kernel(const float* __restrict__ scores,
                                                          const float* __restrict__ fact,
                                                          const float* __restrict__ hin,
                                                          const float* __restrict__ cin,
                                                          unsigned short* __restrict__ topfb,
                                                          float* __restrict__ out) {
    int b = blockIdx.x;
    __shared__ float vals[FF];                 // 16 KiB
    __shared__ float tf[KK][EE];               // 40 KiB
    __shared__ unsigned long long wbest[4];
    __shared__ int sel[KK];
    int t = threadIdx.x;
    int wave = t >> 6, lane = t & 63;

    const float4* sv = (const float4*)(scores + b * FF);
    float4* vv = (float4*)vals;
    for (int i = t; i < FF / 4; i += 256) vv[i] = sv[i];
    __syncthreads();

    // 20 x argmax with packed (sortable-value | (FF-1-idx)) keys; ties -> lower idx
    for (int it = 0; it < KK; ++it) {
        unsigned long long best = 0;
        #pragma unroll
        for (int s = 0; s < FF / 256; ++s) {
            int j = t + s * 256;
            unsigned u = __float_as_uint(vals[j]);
            u ^= ((int)u >> 31) | 0x80000000u;
            unsigned long long key = ((unsigned long long)u << 32) | (unsigned)(FF - 1 - j);
            if (key > best) best = key;
        }
        #pragma unroll
        for (int off = 32; off > 0; off >>= 1) {
            unsigned hi = (unsigned)(best >> 32), lo = (unsigned)best;
            unsigned ohi = __shfl_xor(hi, off, 64);
            unsigned olo = __shfl_xor(lo, off, 64);
            unsigned long long o = ((unsigned long long)ohi << 32) | olo;
            if (o > best) best = o;
        }
        if (lane == 0) wbest[wave] = best;
        __syncthreads();
        if (t == 0) {
            unsigned long long bb = wbest[0];
            if (wbest[1] > bb) bb = wbest[1];
            if (wbest[2] > bb) bb = wbest[2];
            if (wbest[3] > bb) bb = wbest[3];
            int idx = FF - 1 - (int)(bb & 0xFFFFFFFFu);
            sel[it] = idx;
            vals[idx] = -FLT_MAX;
        }
        __syncthreads();
    }

    // gather 20 rows -> tf (LDS, f32) and topfb (global, bf16)
    for (int kk = 0; kk < KK; kk += 2) {
        int k = kk + (t >> 7);
        int e = t & 127;
        int src = sel[k];
        float4 v = *(const float4*)(fact + (((long)b * FF + src) * EE) + e * 4);
        *(float4*)&tf[k][e * 4] = v;
        ushort4 o;
        o.x = bf16rne(v.x); o.y = bf16rne(v.y); o.z = bf16rne(v.z); o.w = bf16rne(v.w);
        *(ushort4*)(topfb + ((size_t)b * KK + k) * EE + e * 4) = o;
    }
    __syncthreads();

    // update: wave w -> (u = h if w<2 else c, layer = w&1)
    const float* u = (wave < 2 ? hin : cin) + ((size_t)(wave & 1) * BB + b) * EE;
    const float4* uv = (const float4*)u;
    float4 ua = uv[lane], ub = uv[64 + lane];
    float sk[KK];
    #pragma unroll
    for (int k = 0; k < KK; ++k) {
        const float4* tv = (const float4*)&tf[k][0];
        float4 ta = tv[lane], tb = tv[64 + lane];
        float d = ua.x * ta.x + ua.y * ta.y + ua.z * ta.z + ua.w * ta.w
                + ub.x * tb.x + ub.y * tb.y + ub.z * tb.z + ub.w * tb.w;
        #pragma unroll
        for (int off = 32; off > 0; off >>= 1) d += __shfl_xor(d, off, 64);
        sk[k] = d;
    }
    float m = sk[0];
    #pragma unroll
    for (int k = 1; k < KK; ++k) m = fmaxf(m, sk[k]);
    float sum = 0.f;
    #pragma unroll
    for (int k = 0; k < KK; ++k) { sk[k] = __expf(sk[k] - m); sum += sk[k]; }
    float inv = 1.f / sum;
    float4 oa = {0, 0, 0, 0}, ob = {0, 0, 0, 0};
    #pragma unroll
    for (int k = 0; k < KK; ++k) {
        float p = sk[k] * inv;
        const float4* tv = (const float4*)&tf[k][0];
        float4 ta = tv[lane], tb = tv[64 + lane];
        oa.x += p * ta.x; oa.y += p * ta.y; oa.z += p * ta.z; oa.w += p * ta.w;
        ob.x += p * tb.x; ob.y += p * tb.y; ob.z += p * tb.z; ob.w += p * tb.w;
    }
    oa.x += ua.x; oa.y += ua.y; oa.z += ua.z; oa.w += ua.w;
    ob.x += ub.x; ob.y += ub.y; ob.z += ub.z; ob.w += ub.w;
    float* obase = out + (size_t)(wave < 2 ? 0 : NLAYER * BB * HH)
                       + ((size_t)(wave & 1) * BB + b) * HH;
    float4* ov = (float4*)obase;
    ov[lane] = oa;
    ov[64 + lane] = ob;
}

// ---------------- K4: fact_M / fact_C via bf16 MFMA ----------------
// block = one (b, mat); 4 waves; wave owns 128 h-cols (8 N-tiles of 16).
// A = topf[b] (20x512, rows 20..31 of the 32-row M-space are garbage, never stored).
// B = W rows (bf16, L2-resident). mfma_f32_16x16x32_bf16:
//   A: lane l holds A[l&15][(l>>4)*8 + j];  B: lane l holds B[(l>>4)*8 + j][l&15]
//   D: lane l, reg r -> D[(l>>4)*4 + r][l&15]
__global__ __launch_bounds__(256) void factmc_kernel(const unsigned short* __restrict__ topfb,
                                                     const unsigned short* __restrict__ Wbf,
                                                     const float* __restrict__ Ab,
                                                     const float* __restrict__ Cb,
                                                     float* __restrict__ out) {
    int b = blockIdx.x, mat = blockIdx.y;
    const unsigned short* W = Wbf + (size_t)mat * HH * EE;
    const float* bias = mat ? Cb : Ab;
    float* O = out + (size_t)2 * NLAYER * BB * HH
                   + (size_t)mat * BB * KK * HH + (size_t)b * KK * HH;

    __shared__ unsigned short tf[32 * EE];   // 32 KiB; rows 20..31 uninit (unused)
    {
        const unsigned short* src = topfb + (size_t)b * KK * EE;
        for (int ib = threadIdx.x; ib < KK * EE / 8; ib += 256) {
            int row = ib >> 6;              // 64 x 16B blocks per 1024B row
            int cb = ib & 63;
            float4 v = *(const float4*)(src + row * EE + cb * 8);
            int byte = (row * 1024 + cb * 16) ^ ((row & 7) << 4);   // XOR swizzle
            *(float4*)((char*)tf + byte) = v;
        }
    }
    __syncthreads();

    int wave = threadIdx.x >> 6, lane = threadIdx.x & 63;
    int lrow = lane & 15, lk = lane >> 4;    // lk in 0..3
    f32x4 acc[2][8];
    #pragma unroll
    for (int m = 0; m < 2; ++m)
        #pragma unroll
        for (int n = 0; n < 8; ++n) acc[m][n] = (f32x4){0, 0, 0, 0};

    int h0 = wave * 128 + lrow;
    const unsigned short* wbase = W + (size_t)h0 * EE + lk * 8;

    #pragma unroll 2
    for (int ks = 0; ks < 16; ++ks) {
        int col2 = (ks * 32 + lk * 8) * 2;
        int byte0 = (lrow * 1024 + col2) ^ ((lrow & 7) << 4);
        bf16x8 a0 = *(const bf16x8*)((const char*)tf + byte0);
        int r1 = 16 + lrow;
        int byte1 = (r1 * 1024 + col2) ^ ((r1 & 7) << 4);
        bf16x8 a1 = *(const bf16x8*)((const char*)tf + byte1);
        #pragma unroll
        for (int n = 0; n < 8; ++n) {
            bf16x8 bfrag = *(const bf16x8*)(wbase + (size_t)n * 16 * EE + ks * 32);
            acc[0][n] = __builtin_amdgcn_mfma_f32_16x16x32_bf16(a0, bfrag, acc[0][n], 0, 0, 0);
            acc[1][n] = __builtin_amdgcn_mfma_f32_16x16x32_bf16(a1, bfrag, acc[1][n], 0, 0, 0);
        }
    }

    #pragma unroll
    for (int n = 0; n < 8; ++n) {
        int h = wave * 128 + n * 16 + lrow;
        float bv = bias[h];
        #pragma unroll
        for (int r = 0; r < 4; ++r) {
            int k0 = lk * 4 + r;
            O[(size_t)k0 * HH + h] = acc[0][n][r] + bv;
            int k1 = 16 + lk * 4 + r;
            if (k1 < KK) O[(size_t)k1 * HH + h] = acc[1][n][r] + bv;
        }
    }
}

extern "C" void kernel_launch(void* const* d_in, const int* in_sizes, int n_in,
                              void* d_out, int out_size, void* d_ws, size_t ws_size,
                              hipStream_t stream) {
    const int* tok = (const int*)d_in[0];
    const float* fact = (const float*)d_in[1];
    const float* hin = (const float*)d_in[2];
    const float* cin = (const float*)d_in[3];
    const float* emb = (const float*)d_in[4];
    const float* Aw = (const float*)d_in[5];
    const float* Ab = (const float*)d_in[6];
    const float* Cw = (const float*)d_in[7];
    const float* Cb = (const float*)d_in[8];
    float* out = (float*)d_out;

    float* ws = (float*)d_ws;
    float* q = ws;                                        // 65536 f
    float* scores = ws + 65536;                           // 524288 f
    unsigned short* topfb = (unsigned short*)(ws + 65536 + 524288);            // 1310720 us
    unsigned short* Wbf = (unsigned short*)(ws + 65536 + 524288 + 655360);     // 524288 us

    q_kernel<<<dim3(BB, 2), 256, 0, stream>>>(tok, emb, q);
    convw_kernel<<<dim3(HH * EE / 1024, 2), 256, 0, stream>>>(Aw, Cw, Wbf);
    scores_kernel<<<dim3(FF / 32, BB), 256, 0, stream>>>(q, fact, scores);
    topk_update_kernel<<<BB, 256, 0, stream>>>(scores, fact, hin, cin, topfb, out);
    factmc_kernel<<<dim3(BB, 2), 256, 0, stream>>>(topfb, Wbf, Ab, Cb, out);
}